// Round 2
// baseline (61448.651 us; speedup 1.0000x reference)
//
#include <hip/hip_runtime.h>
#include <hip/hip_cooperative_groups.h>
#include <math.h>

namespace cg = cooperative_groups;

#define UNITS  256
#define BATCH  32768
#define ROWS   32
#define NCHUNK (BATCH / ROWS)   /* 1024 */
#define TPB    256
#define PAD    36               /* LDS row stride in floats: 144B, 16B-aligned */

#define C_TOL    1.0e-3f
#define C_MINDT  0.01f
#define C_MAXDT  1.0f
#define C_MAXT   1000.0f
#define C_RTOL   0.01f

// ---------------- init: Ws = sym(W) with zero diag; zero scalar slots ----------------
__global__ void init_ws_kernel(const float* __restrict__ W,
                               float* __restrict__ Ws,
                               unsigned* __restrict__ scal)
{
    const int i = blockIdx.x * TPB + threadIdx.x;    // 0..65535
    const int r = i >> 8, c = i & 255;
    float v = 0.5f * (W[(r << 8) + c] + W[(c << 8) + r]);
    if (r == c) v = 0.0f;
    Ws[i] = v;
    if (i < 8) scal[i] = 0u;   // scal[0..2]=err slots, scal[3..5]=pvf slots
}

// ---------------- block max -> one device-scope atomicMax ----------------
__device__ __forceinline__ void blockAtomicMax(unsigned* addr, float v,
                                               float* redbuf, int tid)
{
    #pragma unroll
    for (int o = 32; o > 0; o >>= 1) v = fmaxf(v, __shfl_xor(v, o, 64));
    if ((tid & 63) == 0) redbuf[tid >> 6] = v;
    __syncthreads();
    if (tid == 0) {
        float m = fmaxf(fmaxf(redbuf[0], redbuf[1]), fmaxf(redbuf[2], redbuf[3]));
        atomicMax(addr, __float_as_uint(m));   // v >= 0 -> uint order == float order
    }
    __syncthreads();
}

// ---------------- phase A: xt = x + dt*(ca*ka + ... ) into LDS transposed [k][r] ----------------
template<int NK>
__device__ __forceinline__ void phaseA(float (&xtT)[UNITS][PAD],
    const float* __restrict__ x, int row0,
    const float* __restrict__ ka, const float* __restrict__ kb,
    const float* __restrict__ kc, const float* __restrict__ kd,
    const float* __restrict__ ke,
    float ca, float cb, float cc, float cd, float ce,
    float dt, int tid)
{
    const int col = (tid & 63) << 2;   // float4 column
    const int rb  = tid >> 6;          // 0..3
    #pragma unroll 2
    for (int p = 0; p < 8; ++p) {
        const int r   = (p << 2) + rb;
        const int off = (row0 + r) * UNITS + col;
        float4 xv = *(const float4*)(x + off);
        if constexpr (NK >= 1) {
            float4 v = *(const float4*)(ka + off);
            float sx = ca * v.x, sy = ca * v.y, sz = ca * v.z, sw = ca * v.w;
            if constexpr (NK >= 2) { v = *(const float4*)(kb + off); sx += cb*v.x; sy += cb*v.y; sz += cb*v.z; sw += cb*v.w; }
            if constexpr (NK >= 3) { v = *(const float4*)(kc + off); sx += cc*v.x; sy += cc*v.y; sz += cc*v.z; sw += cc*v.w; }
            if constexpr (NK >= 4) { v = *(const float4*)(kd + off); sx += cd*v.x; sy += cd*v.y; sz += cd*v.z; sw += cd*v.w; }
            if constexpr (NK >= 5) { v = *(const float4*)(ke + off); sx += ce*v.x; sy += ce*v.y; sz += ce*v.z; sw += ce*v.w; }
            xv.x += dt * sx; xv.y += dt * sy; xv.z += dt * sz; xv.w += dt * sw;
        }
        xtT[col + 0][r] = xv.x;
        xtT[col + 1][r] = xv.y;
        xtT[col + 2][r] = xv.z;
        xtT[col + 3][r] = xv.w;
    }
}

// ---------------- phase B: acc[r] = sum_k xt[r][k] * Ws[k][c]  (thread owns col c) ----------------
__device__ __forceinline__ void matmulB(const float (&xtT)[UNITS][PAD],
    const float* __restrict__ Ws, int c, float (&acc)[ROWS])
{
    #pragma unroll
    for (int r = 0; r < ROWS; ++r) acc[r] = 0.0f;
    const float* wp = Ws + c;
    #pragma unroll 2
    for (int k = 0; k < UNITS; ++k) {
        const float w = wp[k * UNITS];                     // coalesced across lanes
        const float4* xr = (const float4*)&xtT[k][0];      // broadcast b128 reads
        #pragma unroll
        for (int q = 0; q < 8; ++q) {
            float4 v = xr[q];
            acc[q*4+0] = fmaf(v.x, w, acc[q*4+0]);
            acc[q*4+1] = fmaf(v.y, w, acc[q*4+1]);
            acc[q*4+2] = fmaf(v.z, w, acc[q*4+2]);
            acc[q*4+3] = fmaf(v.w, w, acc[q*4+3]);
        }
    }
}

// ---------------- epilogue: k = tanh(acc + b) - xt ; optional |k| max ----------------
__device__ __forceinline__ float epilogueK(const float (&acc)[ROWS],
    const float (&xtT)[UNITS][PAD],
    float* __restrict__ kout, float bc, int row0, int c, bool wantMax)
{
    float m = 0.0f;
    #pragma unroll 4
    for (int r = 0; r < ROWS; ++r) {
        const float kv = tanhf(acc[r] + bc) - xtT[c][r];
        kout[(row0 + r) * UNITS + c] = kv;
        if (wantMax) m = fmaxf(m, fabsf(kv));
    }
    return m;
}

// ---------------- stage-6 epilogue: k6 in regs, form x4e/x5e, err, write x5 ----------------
__device__ __forceinline__ float epilogue6(const float (&acc)[ROWS],
    const float (&xtT)[UNITS][PAD],
    const float* __restrict__ x,
    const float* __restrict__ K1, const float* __restrict__ K3,
    const float* __restrict__ K4, const float* __restrict__ K5,
    float* __restrict__ xn,
    float bc, float dt, int row0, int c)
{
    const float d41 = (float)(25.0/216.0),   d43 = (float)(1408.0/2565.0);
    const float d44 = (float)(2197.0/4104.0), d45 = -0.2f;
    const float d51 = (float)(16.0/135.0),   d53 = (float)(6656.0/12825.0);
    const float d54 = (float)(28561.0/56430.0), d55 = (float)(-9.0/50.0);
    const float d56 = (float)(2.0/55.0);
    float m = 0.0f;
    #pragma unroll 4
    for (int r = 0; r < ROWS; ++r) {
        const int off = (row0 + r) * UNITS + c;
        const float k6v = tanhf(acc[r] + bc) - xtT[c][r];
        const float xv  = x[off];
        const float k1v = K1[off], k3v = K3[off], k4v = K4[off], k5v = K5[off];
        const float s4 = d41*k1v + d43*k3v + d44*k4v + d45*k5v;
        const float s5 = d51*k1v + d53*k3v + d54*k4v + d55*k5v + d56*k6v;
        const float x4e = xv + dt * s4;
        const float x5e = xv + dt * s5;
        xn[off] = x5e;
        m = fmaxf(m, fabsf(x5e - x4e));
    }
    return m;
}

// ---------------- persistent cooperative solver ----------------
__global__ void __launch_bounds__(TPB, 4) hopfield_solver(
    float* __restrict__ xA, float* __restrict__ xB,
    const float* __restrict__ bvec, const float* __restrict__ Ws,
    float* __restrict__ K1, float* __restrict__ K2, float* __restrict__ K3,
    float* __restrict__ K4, float* __restrict__ K5,
    unsigned* __restrict__ scal)
{
    cg::grid_group grid = cg::this_grid();
    __shared__ __align__(16) float xtT[UNITS][PAD];
    __shared__ float redbuf[4];
    __shared__ float bc2[2];

    const int tid = threadIdx.x;
    const int c   = tid;
    const float bc = bvec[c];

    float* xc = xA;   // current x (starts in d_out, which holds x0)
    float* xn = xB;
    float t = 0.0f, dt = 0.1f, pvfmax = 0.0f;
    float acc[ROWS];

    // initial k1 = pvf(x0); global max -> pvf slot 2
    {
        float m = 0.0f;
        for (int ch = blockIdx.x; ch < NCHUNK; ch += gridDim.x) {
            const int row0 = ch * ROWS;
            __syncthreads();
            phaseA<0>(xtT, xc, row0, nullptr,nullptr,nullptr,nullptr,nullptr,
                      0,0,0,0,0, dt, tid);
            __syncthreads();
            matmulB(xtT, Ws, c, acc);
            m = fmaxf(m, epilogueK(acc, xtT, K1, bc, row0, c, true));
        }
        blockAtomicMax(&scal[3 + 2], m, redbuf, tid);
    }

    bool pvf_fresh = true;
    int  pvf_slot  = 2;

    for (int it = 0; it < 100000; ++it) {
        // slot resets: err slot for iter it+1 (written pre-sync next iter),
        // pvf slot for this iter (written post-sync this iter). Both are >=2
        // grid-syncs away from their last readers -> race-free.
        if (blockIdx.x == 0 && tid == 0) {
            scal[(it + 1) % 3]  = 0u;
            scal[3 + (it % 3)]  = 0u;
        }

        float em = 0.0f;
        for (int ch = blockIdx.x; ch < NCHUNK; ch += gridDim.x) {
            const int row0 = ch * ROWS;
            // stage 2
            __syncthreads();
            phaseA<1>(xtT, xc, row0, K1,nullptr,nullptr,nullptr,nullptr,
                      0.25f,0,0,0,0, dt, tid);
            __syncthreads();
            matmulB(xtT, Ws, c, acc);
            epilogueK(acc, xtT, K2, bc, row0, c, false);
            // stage 3
            __syncthreads();
            phaseA<2>(xtT, xc, row0, K1,K2,nullptr,nullptr,nullptr,
                      (float)(3.0/32.0), (float)(9.0/32.0), 0,0,0, dt, tid);
            __syncthreads();
            matmulB(xtT, Ws, c, acc);
            epilogueK(acc, xtT, K3, bc, row0, c, false);
            // stage 4
            __syncthreads();
            phaseA<3>(xtT, xc, row0, K1,K2,K3,nullptr,nullptr,
                      (float)(1932.0/2197.0), (float)(-7200.0/2197.0),
                      (float)(7296.0/2197.0), 0,0, dt, tid);
            __syncthreads();
            matmulB(xtT, Ws, c, acc);
            epilogueK(acc, xtT, K4, bc, row0, c, false);
            // stage 5
            __syncthreads();
            phaseA<4>(xtT, xc, row0, K1,K2,K3,K4,nullptr,
                      (float)(439.0/216.0), -8.0f, (float)(3680.0/513.0),
                      (float)(-845.0/4104.0), 0, dt, tid);
            __syncthreads();
            matmulB(xtT, Ws, c, acc);
            epilogueK(acc, xtT, K5, bc, row0, c, false);
            // stage 6 (k6 stays in regs; err + x5 fused)
            __syncthreads();
            phaseA<5>(xtT, xc, row0, K1,K2,K3,K4,K5,
                      (float)(-8.0/27.0), 2.0f, (float)(-3544.0/2565.0),
                      (float)(1859.0/4104.0), (float)(-11.0/40.0), dt, tid);
            __syncthreads();
            matmulB(xtT, Ws, c, acc);
            em = fmaxf(em, epilogue6(acc, xtT, xc, K1, K3, K4, K5, xn,
                                     bc, dt, row0, c));
        }
        blockAtomicMax(&scal[it % 3], em, redbuf, tid);

        grid.sync();   // the one grid sync per iteration

        if (tid == 0) {
            bc2[0] = __uint_as_float(atomicMax(&scal[it % 3], 0u));      // err (final)
            bc2[1] = __uint_as_float(atomicMax(&scal[3 + pvf_slot], 0u)); // pvf (final)
        }
        __syncthreads();
        const float err = bc2[0];
        if (pvf_fresh) pvfmax = bc2[1];

        // reference checks cond BEFORE the body that we just (speculatively) ran
        if (!((t <= C_MAXT) && (pvfmax >= C_RTOL))) break;

        const bool accept = (err < C_TOL) || (dt <= C_MINDT);
        float dtn = 0.9f * dt * powf(C_TOL / (err + 1e-12f), 0.2f);
        dtn = fminf(fmaxf(dtn, C_MINDT), C_MAXDT);

        if (accept) {
            t = t + dt;
            float* tmp = xc; xc = xn; xn = tmp;   // x <- x5 (uniform swap)
            // k1_new = pvf(x_new) (== cond's pvf and next step's k1)
            float m = 0.0f;
            for (int ch = blockIdx.x; ch < NCHUNK; ch += gridDim.x) {
                const int row0 = ch * ROWS;
                __syncthreads();
                phaseA<0>(xtT, xc, row0, nullptr,nullptr,nullptr,nullptr,nullptr,
                          0,0,0,0,0, dt, tid);
                __syncthreads();
                matmulB(xtT, Ws, c, acc);
                m = fmaxf(m, epilogueK(acc, xtT, K1, bc, row0, c, true));
            }
            blockAtomicMax(&scal[3 + (it % 3)], m, redbuf, tid);
            pvf_slot = it % 3;
            pvf_fresh = true;
        } else {
            pvf_fresh = false;
        }
        dt = dtn;
    }

    // final x must end up in d_out (block-local rows; no sync needed)
    if (xc != xA) {
        for (int ch = blockIdx.x; ch < NCHUNK; ch += gridDim.x) {
            const int base = ch * ROWS * UNITS;
            for (int i = tid; i < ROWS * UNITS / 4; i += TPB) {
                ((float4*)(xA + base))[i] = ((const float4*)(xc + base))[i];
            }
        }
    }
}

// ---------------- host ----------------
extern "C" void kernel_launch(void* const* d_in, const int* in_sizes, int n_in,
                              void* d_out, int out_size, void* d_ws, size_t ws_size,
                              hipStream_t stream)
{
    const float* x0 = (const float*)d_in[0];
    const float* W  = (const float*)d_in[1];
    const float* b  = (const float*)d_in[2];
    float* xA = (float*)d_out;

    const size_t kbytes = (size_t)BATCH * UNITS * sizeof(float);   // 32 MiB
    char* ws = (char*)d_ws;
    unsigned* scal = (unsigned*)ws;                                 // 32 B used
    float* Ws = (float*)(ws + 4096);                                // 256 KiB
    char* kb  = ws + 4096 + (size_t)UNITS * UNITS * sizeof(float);
    float* K1 = (float*)(kb + 0 * kbytes);
    float* K2 = (float*)(kb + 1 * kbytes);
    float* K3 = (float*)(kb + 2 * kbytes);
    float* K4 = (float*)(kb + 3 * kbytes);
    float* K5 = (float*)(kb + 4 * kbytes);
    float* xB = (float*)(kb + 5 * kbytes);

    const size_t req = 4096 + (size_t)UNITS * UNITS * sizeof(float) + 6 * kbytes; // ~192.3 MB
    if (ws_size < req) return;  // insufficient scratch: fail cleanly, don't corrupt

    init_ws_kernel<<<(UNITS * UNITS) / TPB, TPB, 0, stream>>>(W, Ws, scal);
    (void)hipMemcpyAsync(xA, x0, kbytes, hipMemcpyDeviceToDevice, stream);

    int nb = 0;
    if (hipOccupancyMaxActiveBlocksPerMultiprocessor(&nb, hopfield_solver, TPB, 0) != hipSuccess || nb < 1)
        nb = 1;
    int ncu = 0;
    if (hipDeviceGetAttribute(&ncu, hipDeviceAttributeMultiprocessorCount, 0) != hipSuccess || ncu < 1)
        ncu = 256;
    int gridsz = nb * ncu;
    if (gridsz > NCHUNK) gridsz = NCHUNK;
    if (gridsz < 1) gridsz = 1;

    void* args[10];
    args[0] = (void*)&xA; args[1] = (void*)&xB; args[2] = (void*)&b;  args[3] = (void*)&Ws;
    args[4] = (void*)&K1; args[5] = (void*)&K2; args[6] = (void*)&K3; args[7] = (void*)&K4;
    args[8] = (void*)&K5; args[9] = (void*)&scal;
    (void)hipLaunchCooperativeKernel(hopfield_solver, dim3(gridsz), dim3(TPB), args, 0u, stream);
}

// Round 4
// 13530.501 us; speedup vs baseline: 4.5415x; 4.5415x over previous
//
#include <hip/hip_runtime.h>
#include <hip/hip_cooperative_groups.h>
#include <math.h>

namespace cg = cooperative_groups;

#define UNITS  256
#define BATCH  32768
#define R      16                 /* rows per chunk */
#define NCHUNK (BATCH / R)        /* 2048 */
#define TPB    512

typedef float f32x4 __attribute__((ext_vector_type(4)));
typedef short s16x8 __attribute__((ext_vector_type(8)));

// ---- index helpers -------------------------------------------------------
// f32 state buffers (x, K1..K5): [ks(8)][h(2)][g(4)][r(16)][s4(4)] = 4096 f32
__device__ __forceinline__ int sidx(int r, int n) {
    return ((n >> 5) << 9) + (((n >> 2) & 1) << 8) + (((n >> 3) & 3) << 6) + (r << 2) + (n & 3);
}
// bf16 frag buffers (xt hi/lo): [ks(8)][g(4)][r(16)][s(8)] = 4096 bf16 (u16 idx)
__device__ __forceinline__ int fidx(int r, int n) {
    return ((n >> 5) << 9) + (((n >> 3) & 3) << 7) + (r << 3) + (n & 7);
}

__device__ __forceinline__ unsigned bf16rn_bits(float v) {
    unsigned u = __float_as_uint(v);
    return (u + 0x7FFFu + ((u >> 16) & 1u)) >> 16;
}

// split 8 f32 -> bf16 hi/lo fragments, store one b128 each.
// fu is the FRAGMENT unit index (== tid): [ks(8)][g(4)][r(16)] -> 512 units.
__device__ __forceinline__ void splitStore(s16x8* XH, s16x8* XL, int fu, f32x4 a, f32x4 b)
{
    s16x8 h, l;
    #pragma unroll
    for (int j = 0; j < 4; ++j) {
        unsigned hb = bf16rn_bits(a[j]);
        float hf = __uint_as_float(hb << 16);
        unsigned lb = bf16rn_bits(a[j] - hf);
        h[j] = (short)hb; l[j] = (short)lb;
    }
    #pragma unroll
    for (int j = 0; j < 4; ++j) {
        unsigned hb = bf16rn_bits(b[j]);
        float hf = __uint_as_float(hb << 16);
        unsigned lb = bf16rn_bits(b[j] - hf);
        h[4 + j] = (short)hb; l[4 + j] = (short)lb;
    }
    XH[fu] = h; XL[fu] = l;
}

// xt = x + c1*Ka + ... (dt-premultiplied coeffs), split into frag buffers
template<int NK>
__device__ __forceinline__ void phaseAf(const float* Xs,
    const float* Ka, const float* Kb, const float* Kc, const float* Kd, const float* Ke,
    float c1, float c2, float c3, float c4, float c5,
    s16x8* XH, s16x8* XL, int pidx4, int fu)
{
    const f32x4* X4 = (const f32x4*)Xs;
    f32x4 a = X4[pidx4], b = X4[pidx4 + 64];
    #define ACCK(P, C) { const f32x4* q = (const f32x4*)(P); f32x4 u = q[pidx4], v = q[pidx4 + 64]; \
        _Pragma("unroll") for (int j = 0; j < 4; ++j) { a[j] += (C) * u[j]; b[j] += (C) * v[j]; } }
    if constexpr (NK >= 1) ACCK(Ka, c1)
    if constexpr (NK >= 2) ACCK(Kb, c2)
    if constexpr (NK >= 3) ACCK(Kc, c3)
    if constexpr (NK >= 4) ACCK(Kd, c4)
    if constexpr (NK >= 5) ACCK(Ke, c5)
    #undef ACCK
    splitStore(XH, XL, fu, a, b);
}

__device__ __forceinline__ void blockAtomicMax2(unsigned* addr, float v, float* redbuf, int tid)
{
    #pragma unroll
    for (int o = 32; o > 0; o >>= 1) v = fmaxf(v, __shfl_xor(v, o, 64));
    if ((tid & 63) == 0) redbuf[tid >> 6] = v;
    __syncthreads();
    if (tid == 0) {
        float m = redbuf[0];
        #pragma unroll
        for (int i = 1; i < 8; ++i) m = fmaxf(m, redbuf[i]);
        atomicMax(addr, __float_as_uint(m));   // values >= 0: uint order == float order
    }
    __syncthreads();
}

// ---- init: build symmetric zero-diag Ws, split to bf16 hi/lo fragment order ----
__global__ void init_ws_kernel(const float* __restrict__ W,
                               unsigned short* __restrict__ WfH,
                               unsigned short* __restrict__ WfL,
                               unsigned* __restrict__ scal)
{
    const int i = blockIdx.x * 256 + threadIdx.x;    // 0..65535
    const int k = i >> 8, n = i & 255;
    float v = 0.5f * (W[(k << 8) + n] + W[(n << 8) + k]);
    if (k == n) v = 0.0f;
    unsigned hb = bf16rn_bits(v);
    float hf = __uint_as_float(hb << 16);
    unsigned lb = bf16rn_bits(v - hf);
    // fragment order: [nt(16)][ks(8)][lane(64)][slot(8)]
    const int nt = n >> 4, ks = k >> 5;
    const int lane = (n & 15) + (((k >> 3) & 3) << 4);
    const int slot = k & 7;
    const int off = ((nt * 8 + ks) * 64 + lane) * 8 + slot;
    WfH[off] = (unsigned short)hb;
    WfL[off] = (unsigned short)lb;
    if (i < 8) scal[i] = 0u;
}

// ---- persistent cooperative solver --------------------------------------
__global__ void __launch_bounds__(TPB, 2) hopfield_solver(
    float* __restrict__ xA, float* __restrict__ xB,
    const float* __restrict__ bvec,
    const s16x8* __restrict__ WfH, const s16x8* __restrict__ WfL,
    unsigned* __restrict__ scal)
{
    cg::grid_group grid = cg::this_grid();
    __shared__ __align__(16) float Xs[4096];
    __shared__ __align__(16) float K1s[4096], K2s[4096], K3s[4096], K4s[4096], K5s[4096];
    __shared__ __align__(16) s16x8 XH[512], XL[512];
    __shared__ float redbuf[8];
    __shared__ float bc2[2];

    const int tid = threadIdx.x;
    const int l = tid & 63, w = tid >> 6;

    // phaseA / load mapping: thread -> (r, ks, g), one s16x8 unit (8 cols)
    const int pr = tid & 15, pg = (tid >> 4) & 3, pks = tid >> 6;
    const int pidx4 = (pks << 7) + (pg << 4) + pr;   // f32x4 state unit; +64 for h=1
    const int pcol  = (pks << 5) + (pg << 3);        // global col base
    // fragment unit index for the same (r, cols) = pks*64 + pg*16 + pr == tid

    // matmul / epilogue mapping: wave w owns cols [w*32, w*32+32)
    const int n0 = w * 32 + (l & 15);
    const int n1 = n0 + 16;
    const int mb = (l >> 4) << 2;                    // row base; +reg(0..3)
    const float bn0 = bvec[n0], bn1 = bvec[n1];
    const int sb0 = sidx(0, n0), sb1 = sidx(0, n1);
    const int fb0 = fidx(0, n0), fb1 = fidx(0, n1);

    // preload Ws fragments for this wave's two n-tiles (persistent, 128 VGPR)
    s16x8 BH0[8], BL0[8], BH1[8], BL1[8];
    {
        const int nt0 = w * 2;
        #pragma unroll
        for (int ks = 0; ks < 8; ++ks) {
            BH0[ks] = WfH[(nt0 * 8 + ks) * 64 + l];
            BL0[ks] = WfL[(nt0 * 8 + ks) * 64 + l];
            BH1[ks] = WfH[((nt0 + 1) * 8 + ks) * 64 + l];
            BL1[ks] = WfL[((nt0 + 1) * 8 + ks) * 64 + l];
        }
    }

    const unsigned short* XHu = (const unsigned short*)XH;
    const unsigned short* XLu = (const unsigned short*)XL;

    auto xtAt = [&](int fb, int m) -> float {
        int o = fb + (m << 3);
        return __uint_as_float((unsigned)XHu[o] << 16) + __uint_as_float((unsigned)XLu[o] << 16);
    };

    auto matmul = [&](f32x4& acc0, f32x4& acc1) {
        #pragma unroll
        for (int ks = 0; ks < 8; ++ks) {
            s16x8 aH = XH[ks * 64 + l];
            s16x8 aL = XL[ks * 64 + l];
            acc0 = __builtin_amdgcn_mfma_f32_16x16x32_bf16(aH, BH0[ks], acc0, 0, 0, 0);
            acc1 = __builtin_amdgcn_mfma_f32_16x16x32_bf16(aH, BH1[ks], acc1, 0, 0, 0);
            acc0 = __builtin_amdgcn_mfma_f32_16x16x32_bf16(aH, BL0[ks], acc0, 0, 0, 0);
            acc1 = __builtin_amdgcn_mfma_f32_16x16x32_bf16(aH, BL1[ks], acc1, 0, 0, 0);
            acc0 = __builtin_amdgcn_mfma_f32_16x16x32_bf16(aL, BH0[ks], acc0, 0, 0, 0);
            acc1 = __builtin_amdgcn_mfma_f32_16x16x32_bf16(aL, BH1[ks], acc1, 0, 0, 0);
        }
    };

    auto epiK = [&](float* Ks, f32x4 acc0, f32x4 acc1, bool wantMax) -> float {
        float mx = 0.0f;
        #pragma unroll
        for (int g2 = 0; g2 < 4; ++g2) {
            int m = mb + g2;
            float kv0 = tanhf(acc0[g2] + bn0) - xtAt(fb0, m);
            float kv1 = tanhf(acc1[g2] + bn1) - xtAt(fb1, m);
            Ks[sb0 + (m << 2)] = kv0;
            Ks[sb1 + (m << 2)] = kv1;
            if (wantMax) mx = fmaxf(mx, fmaxf(fabsf(kv0), fabsf(kv1)));
        }
        return mx;
    };

    float* xc = xA;   // current x (d_out holds x0)
    float* xn = xB;
    float t = 0.0f, dt = 0.1f;

    for (int it = 0; it < 100000; ++it) {
        if (blockIdx.x == 0 && tid == 0) {
            scal[(it + 1) % 3] = 0u;          // err slot for next iter
            scal[3 + (it + 1) % 3] = 0u;      // pvf slot for next iter
        }

        // dt-premultiplied RKF coefficients (uniform scalars)
        const float a21 = 0.25f * dt;
        const float a31 = (float)(3.0 / 32.0) * dt,   a32 = (float)(9.0 / 32.0) * dt;
        const float a41 = (float)(1932.0 / 2197.0) * dt, a42 = (float)(-7200.0 / 2197.0) * dt,
                    a43 = (float)(7296.0 / 2197.0) * dt;
        const float a51 = (float)(439.0 / 216.0) * dt, a52 = -8.0f * dt,
                    a53 = (float)(3680.0 / 513.0) * dt, a54 = (float)(-845.0 / 4104.0) * dt;
        const float a61 = (float)(-8.0 / 27.0) * dt,  a62 = 2.0f * dt,
                    a63 = (float)(-3544.0 / 2565.0) * dt, a64 = (float)(1859.0 / 4104.0) * dt,
                    a65 = (float)(-11.0 / 40.0) * dt;
        const float c41 = (float)(25.0 / 216.0) * dt, c43 = (float)(1408.0 / 2565.0) * dt,
                    c44 = (float)(2197.0 / 4104.0) * dt, c45 = -0.2f * dt;
        const float c51 = (float)(16.0 / 135.0) * dt, c53 = (float)(6656.0 / 12825.0) * dt,
                    c54 = (float)(28561.0 / 56430.0) * dt, c55 = (float)(-9.0 / 50.0) * dt,
                    c56 = (float)(2.0 / 55.0) * dt;

        float em = 0.0f, pm = 0.0f;

        for (int ch = blockIdx.x; ch < NCHUNK; ch += gridDim.x) {
            const int row0 = ch * R;

            // load x chunk -> LDS (state order) + split to frag buffers
            {
                const f32x4* G = (const f32x4*)(xc + (size_t)(row0 + pr) * UNITS + pcol);
                f32x4 a = G[0], b = G[1];
                f32x4* X4 = (f32x4*)Xs;
                X4[pidx4] = a; X4[pidx4 + 64] = b;
                splitStore(XH, XL, tid, a, b);
            }
            __syncthreads();

            f32x4 acc0, acc1;

            // stage 1: k1 = pvf(x)  (also the stop-condition pvf)
            acc0 = {0.f, 0.f, 0.f, 0.f}; acc1 = {0.f, 0.f, 0.f, 0.f};
            matmul(acc0, acc1);
            pm = fmaxf(pm, epiK(K1s, acc0, acc1, true));
            __syncthreads();

            // stage 2
            phaseAf<1>(Xs, K1s, nullptr, nullptr, nullptr, nullptr,
                       a21, 0, 0, 0, 0, XH, XL, pidx4, tid);
            __syncthreads();
            acc0 = {0.f, 0.f, 0.f, 0.f}; acc1 = {0.f, 0.f, 0.f, 0.f};
            matmul(acc0, acc1);
            epiK(K2s, acc0, acc1, false);
            __syncthreads();

            // stage 3
            phaseAf<2>(Xs, K1s, K2s, nullptr, nullptr, nullptr,
                       a31, a32, 0, 0, 0, XH, XL, pidx4, tid);
            __syncthreads();
            acc0 = {0.f, 0.f, 0.f, 0.f}; acc1 = {0.f, 0.f, 0.f, 0.f};
            matmul(acc0, acc1);
            epiK(K3s, acc0, acc1, false);
            __syncthreads();

            // stage 4
            phaseAf<3>(Xs, K1s, K2s, K3s, nullptr, nullptr,
                       a41, a42, a43, 0, 0, XH, XL, pidx4, tid);
            __syncthreads();
            acc0 = {0.f, 0.f, 0.f, 0.f}; acc1 = {0.f, 0.f, 0.f, 0.f};
            matmul(acc0, acc1);
            epiK(K4s, acc0, acc1, false);
            __syncthreads();

            // stage 5
            phaseAf<4>(Xs, K1s, K2s, K3s, K4s, nullptr,
                       a51, a52, a53, a54, 0, XH, XL, pidx4, tid);
            __syncthreads();
            acc0 = {0.f, 0.f, 0.f, 0.f}; acc1 = {0.f, 0.f, 0.f, 0.f};
            matmul(acc0, acc1);
            epiK(K5s, acc0, acc1, false);
            __syncthreads();

            // stage 6 + fused err/x5 epilogue
            phaseAf<5>(Xs, K1s, K2s, K3s, K4s, K5s,
                       a61, a62, a63, a64, a65, XH, XL, pidx4, tid);
            __syncthreads();
            acc0 = {0.f, 0.f, 0.f, 0.f}; acc1 = {0.f, 0.f, 0.f, 0.f};
            matmul(acc0, acc1);
            {
                #pragma unroll
                for (int g2 = 0; g2 < 4; ++g2) {
                    int m = mb + g2;
                    int o0 = sb0 + (m << 2), o1 = sb1 + (m << 2);
                    float k60 = tanhf(acc0[g2] + bn0) - xtAt(fb0, m);
                    float k61 = tanhf(acc1[g2] + bn1) - xtAt(fb1, m);
                    float xv0 = Xs[o0], xv1 = Xs[o1];
                    float k10 = K1s[o0], k11 = K1s[o1];
                    float k30 = K3s[o0], k31 = K3s[o1];
                    float k40 = K4s[o0], k41 = K4s[o1];
                    float k50 = K5s[o0], k51 = K5s[o1];
                    float x4e0 = xv0 + c41 * k10 + c43 * k30 + c44 * k40 + c45 * k50;
                    float x5e0 = xv0 + c51 * k10 + c53 * k30 + c54 * k40 + c55 * k50 + c56 * k60;
                    float x4e1 = xv1 + c41 * k11 + c43 * k31 + c44 * k41 + c45 * k51;
                    float x5e1 = xv1 + c51 * k11 + c53 * k31 + c54 * k41 + c55 * k51 + c56 * k61;
                    xn[(size_t)(row0 + m) * UNITS + n0] = x5e0;
                    xn[(size_t)(row0 + m) * UNITS + n1] = x5e1;
                    em = fmaxf(em, fmaxf(fabsf(x5e0 - x4e0), fabsf(x5e1 - x4e1)));
                }
            }
            __syncthreads();   // protect Xs/K/XH/XL before next chunk overwrites
        }

        blockAtomicMax2(&scal[it % 3], em, redbuf, tid);
        blockAtomicMax2(&scal[3 + it % 3], pm, redbuf, tid);

        grid.sync();

        if (tid == 0) {
            bc2[0] = __uint_as_float(atomicMax(&scal[it % 3], 0u));       // global err
            bc2[1] = __uint_as_float(atomicMax(&scal[3 + it % 3], 0u));   // global pvf max
        }
        __syncthreads();
        const float err = bc2[0];
        const float pvfmax = bc2[1];

        // reference checks cond BEFORE the body we just (speculatively) ran
        if (!((t <= 1000.0f) && (pvfmax >= 0.01f))) break;

        const bool accept = (err < 1.0e-3f) || (dt <= 0.01f);
        float dtn = 0.9f * dt * powf(1.0e-3f / (err + 1e-12f), 0.2f);
        dtn = fminf(fmaxf(dtn, 0.01f), 1.0f);

        if (accept) {
            t = t + dt;
            float* tmp = xc; xc = xn; xn = tmp;
        }
        dt = dtn;
    }

    // final x must end in d_out (block-local rows; no grid sync needed)
    if (xc != xA) {
        for (int ch = blockIdx.x; ch < NCHUNK; ch += gridDim.x) {
            const float* src = xc + (size_t)ch * R * UNITS;
            float* dst = xA + (size_t)ch * R * UNITS;
            for (int i = tid; i < R * UNITS / 4; i += TPB)
                ((f32x4*)dst)[i] = ((const f32x4*)src)[i];
        }
    }
}

// ---- host ----------------------------------------------------------------
extern "C" void kernel_launch(void* const* d_in, const int* in_sizes, int n_in,
                              void* d_out, int out_size, void* d_ws, size_t ws_size,
                              hipStream_t stream)
{
    const float* x0 = (const float*)d_in[0];
    const float* W  = (const float*)d_in[1];
    const float* b  = (const float*)d_in[2];
    float* xA = (float*)d_out;

    const size_t xbytes = (size_t)BATCH * UNITS * sizeof(float);      // 32 MiB
    const size_t wfrag  = (size_t)UNITS * UNITS * sizeof(unsigned short); // 128 KiB

    char* ws = (char*)d_ws;
    unsigned* scal = (unsigned*)ws;                      // 32 B used
    unsigned short* WfH = (unsigned short*)(ws + 4096);
    unsigned short* WfL = (unsigned short*)(ws + 4096 + wfrag);
    float* xB = (float*)(ws + 4096 + 2 * wfrag);

    const size_t req = 4096 + 2 * wfrag + xbytes;        // ~32.3 MB
    if (ws_size < req) return;

    init_ws_kernel<<<(UNITS * UNITS) / 256, 256, 0, stream>>>(W, WfH, WfL, scal);
    (void)hipMemcpyAsync(xA, x0, xbytes, hipMemcpyDeviceToDevice, stream);

    int nb = 0;
    if (hipOccupancyMaxActiveBlocksPerMultiprocessor(&nb, hopfield_solver, TPB, 0) != hipSuccess || nb < 1)
        nb = 1;
    int ncu = 0;
    if (hipDeviceGetAttribute(&ncu, hipDeviceAttributeMultiprocessorCount, 0) != hipSuccess || ncu < 1)
        ncu = 256;
    int gridsz = nb * ncu;
    if (gridsz > NCHUNK) gridsz = NCHUNK;
    if (gridsz < 1) gridsz = 1;

    void* args[6];
    args[0] = (void*)&xA; args[1] = (void*)&xB; args[2] = (void*)&b;
    args[3] = (void*)&WfH; args[4] = (void*)&WfL; args[5] = (void*)&scal;
    (void)hipLaunchCooperativeKernel(hopfield_solver, dim3(gridsz), dim3(TPB), args, 0u, stream);
}

// Round 5
// 8078.871 us; speedup vs baseline: 7.6061x; 1.6748x over previous
//
#include <hip/hip_runtime.h>
#include <hip/hip_cooperative_groups.h>
#include <math.h>

namespace cg = cooperative_groups;

#define UNITS  256
#define BATCH  32768
#define R      16                 /* rows per chunk */
#define NCHUNK (BATCH / R)        /* 2048 */
#define TPB    512

typedef float f32x4 __attribute__((ext_vector_type(4)));
typedef short s16x8 __attribute__((ext_vector_type(8)));

__device__ __forceinline__ unsigned bf16rn_bits(float v) {
    unsigned u = __float_as_uint(v);
    return (u + 0x7FFFu + ((u >> 16) & 1u)) >> 16;   // round-to-nearest-even
}

__device__ __forceinline__ float tanh_fast(float v) {
    // tanh(x) = sign(x) * (1 - 2/(exp(2|x|)+1)); |x| here <= ~3, no overflow
    float a = fabsf(v);
    float e = __expf(a + a);
    float r = 1.0f - 2.0f / (e + 1.0f);
    return copysignf(r, v);
}

// padded frag layout: unit (16B) -> u16 offset; 16B pad after every 8 units
// (makes both scattered b16 writes and per-lane b128 reads bank-conflict-free)
__device__ __forceinline__ int puidx(int unit) {
    return (unit << 3) + ((unit >> 3) << 3);
}

__device__ __forceinline__ void blockAtomicMax2(unsigned* addr, float v, float* redbuf, int tid)
{
    #pragma unroll
    for (int o = 32; o > 0; o >>= 1) v = fmaxf(v, __shfl_xor(v, o, 64));
    if ((tid & 63) == 0) redbuf[tid >> 6] = v;
    __syncthreads();
    if (tid == 0) {
        float m = redbuf[0];
        #pragma unroll
        for (int i = 1; i < 8; ++i) m = fmaxf(m, redbuf[i]);
        atomicMax(addr, __float_as_uint(m));   // values >= 0: uint order == float order
    }
    __syncthreads();
}

// ---- init: symmetric zero-diag Ws, split to bf16 hi/lo B-fragment order ----
__global__ void init_ws_kernel(const float* __restrict__ W,
                               unsigned short* __restrict__ WfH,
                               unsigned short* __restrict__ WfL,
                               unsigned* __restrict__ scal)
{
    const int i = blockIdx.x * 256 + threadIdx.x;    // 0..65535
    const int k = i >> 8, n = i & 255;
    float v = 0.5f * (W[(k << 8) + n] + W[(n << 8) + k]);
    if (k == n) v = 0.0f;
    unsigned hb = bf16rn_bits(v);
    float hf = __uint_as_float(hb << 16);
    unsigned lb = bf16rn_bits(v - hf);
    // fragment order: [nt(16)][ks(8)][lane(64)][slot(8)]
    const int nt = n >> 4, ks = k >> 5;
    const int lane = (n & 15) + (((k >> 3) & 3) << 4);
    const int slot = k & 7;
    const int off = ((nt * 8 + ks) * 64 + lane) * 8 + slot;
    WfH[off] = (unsigned short)hb;
    WfL[off] = (unsigned short)lb;
    if (i < 8) scal[i] = 0u;
}

// ---- persistent cooperative solver --------------------------------------
__global__ void __launch_bounds__(TPB, 2) hopfield_solver(
    float* __restrict__ xA, float* __restrict__ xB,
    const float* __restrict__ bvec,
    const s16x8* __restrict__ WfH, const s16x8* __restrict__ WfL,
    unsigned* __restrict__ scal)
{
    cg::grid_group grid = cg::this_grid();
    __shared__ __align__(16) unsigned short XH[2][4608];   // 2 x 9216 B
    __shared__ __align__(16) unsigned short XL[2][4608];
    __shared__ float redbuf[8];
    __shared__ float bc2[2];

    const int tid = threadIdx.x;
    const int l = tid & 63, w = tid >> 6;

    // C-layout element ownership: cols n0, n1; rows mb..mb+3
    const int n0 = w * 32 + (l & 15);
    const int n1 = n0 + 16;
    const int mb = (l >> 4) << 2;
    const float bn0 = bvec[n0], bn1 = bvec[n1];

    // A-frag write targets (element (m, n) -> unit ks*64 + gk*16 + m, slot n&7)
    const int s_slot = l & 7;
    const int gk0 = (l & 15) >> 3;
    const int pb0 = puidx(w * 64 + gk0 * 16 + mb) + s_slot;       // + 8*g2
    const int pb1 = puidx(w * 64 + (gk0 + 2) * 16 + mb) + s_slot; // + 8*g2
    // A-frag read base for lane l (unit = ks*64 + l -> puidx = ks*576 + lbase)
    const int lbase = (l << 3) + ((l >> 3) << 3);

    // preload Ws B-fragments for this wave's two n-tiles (128 VGPR, persistent)
    s16x8 BH0[8], BL0[8], BH1[8], BL1[8];
    {
        const int nt0 = w * 2;
        #pragma unroll
        for (int ks = 0; ks < 8; ++ks) {
            BH0[ks] = WfH[(nt0 * 8 + ks) * 64 + l];
            BL0[ks] = WfL[(nt0 * 8 + ks) * 64 + l];
            BH1[ks] = WfH[((nt0 + 1) * 8 + ks) * 64 + l];
            BL1[ks] = WfL[((nt0 + 1) * 8 + ks) * 64 + l];
        }
    }

    // split 8 f32 (4 rows x 2 cols) into bf16 hi/lo frags and store to buffer p
    auto writeFrag = [&](int p, const float (&v0)[4], const float (&v1)[4]) {
        #pragma unroll
        for (int g2 = 0; g2 < 4; ++g2) {
            unsigned hb = bf16rn_bits(v0[g2]);
            unsigned lb = bf16rn_bits(v0[g2] - __uint_as_float(hb << 16));
            XH[p][pb0 + 8 * g2] = (unsigned short)hb;
            XL[p][pb0 + 8 * g2] = (unsigned short)lb;
            hb = bf16rn_bits(v1[g2]);
            lb = bf16rn_bits(v1[g2] - __uint_as_float(hb << 16));
            XH[p][pb1 + 8 * g2] = (unsigned short)hb;
            XL[p][pb1 + 8 * g2] = (unsigned short)lb;
        }
    };

    auto matmul = [&](int p, f32x4& acc0, f32x4& acc1) {
        #pragma unroll
        for (int ks = 0; ks < 8; ++ks) {
            const s16x8 aH = *(const s16x8*)&XH[p][ks * 576 + lbase];
            const s16x8 aL = *(const s16x8*)&XL[p][ks * 576 + lbase];
            acc0 = __builtin_amdgcn_mfma_f32_16x16x32_bf16(aH, BH0[ks], acc0, 0, 0, 0);
            acc1 = __builtin_amdgcn_mfma_f32_16x16x32_bf16(aH, BH1[ks], acc1, 0, 0, 0);
            acc0 = __builtin_amdgcn_mfma_f32_16x16x32_bf16(aH, BL0[ks], acc0, 0, 0, 0);
            acc1 = __builtin_amdgcn_mfma_f32_16x16x32_bf16(aH, BL1[ks], acc1, 0, 0, 0);
            acc0 = __builtin_amdgcn_mfma_f32_16x16x32_bf16(aL, BH0[ks], acc0, 0, 0, 0);
            acc1 = __builtin_amdgcn_mfma_f32_16x16x32_bf16(aL, BH1[ks], acc1, 0, 0, 0);
        }
    };

    float* xc = xA;   // current x (d_out holds x0)
    float* xn = xB;
    float t = 0.0f, dt = 0.1f;

    for (int it = 0; it < 100000; ++it) {
        if (blockIdx.x == 0 && tid == 0) {
            scal[(it + 1) % 3] = 0u;          // err slot for next iter
            scal[3 + (it + 1) % 3] = 0u;      // pvf slot for next iter
        }

        // dt-premultiplied RKF coefficients (wave-uniform scalars -> SGPR)
        const float a21 = 0.25f * dt;
        const float a31 = (float)(3.0 / 32.0) * dt,   a32 = (float)(9.0 / 32.0) * dt;
        const float a41 = (float)(1932.0 / 2197.0) * dt, a42 = (float)(-7200.0 / 2197.0) * dt,
                    a43 = (float)(7296.0 / 2197.0) * dt;
        const float a51 = (float)(439.0 / 216.0) * dt, a52 = -8.0f * dt,
                    a53 = (float)(3680.0 / 513.0) * dt, a54 = (float)(-845.0 / 4104.0) * dt;
        const float a61 = (float)(-8.0 / 27.0) * dt,  a62 = 2.0f * dt,
                    a63 = (float)(-3544.0 / 2565.0) * dt, a64 = (float)(1859.0 / 4104.0) * dt,
                    a65 = (float)(-11.0 / 40.0) * dt;
        const float c41 = (float)(25.0 / 216.0) * dt, c43 = (float)(1408.0 / 2565.0) * dt,
                    c44 = (float)(2197.0 / 4104.0) * dt, c45 = -0.2f * dt;
        const float c51 = (float)(16.0 / 135.0) * dt, c53 = (float)(6656.0 / 12825.0) * dt,
                    c54 = (float)(28561.0 / 56430.0) * dt, c55 = (float)(-9.0 / 50.0) * dt,
                    c56 = (float)(2.0 / 55.0) * dt;

        float em = 0.0f, pm = 0.0f;

        for (int ch = blockIdx.x; ch < NCHUNK; ch += gridDim.x) {
            const size_t rowbase = (size_t)(ch * R + mb) * UNITS;

            float xr0[4], xr1[4];
            float k1r0[4], k1r1[4], k2r0[4], k2r1[4], k3r0[4], k3r1[4];
            float k4r0[4], k4r1[4], k5r0[4], k5r1[4];
            float xt0[4], xt1[4];
            f32x4 acc0, acc1;

            // load x chunk straight to registers (C-layout)
            #pragma unroll
            for (int g = 0; g < 4; ++g) {
                xr0[g] = xc[rowbase + (size_t)g * UNITS + n0];
                xr1[g] = xc[rowbase + (size_t)g * UNITS + n1];
            }

            // stage 1: k1 = pvf(x) (doubles as the stop-condition pvf)
            writeFrag(1, xr0, xr1);
            __syncthreads();
            acc0 = {0.f, 0.f, 0.f, 0.f}; acc1 = {0.f, 0.f, 0.f, 0.f};
            matmul(1, acc0, acc1);
            #pragma unroll
            for (int g = 0; g < 4; ++g) {
                float kv0 = tanh_fast(acc0[g] + bn0) - xr0[g];
                float kv1 = tanh_fast(acc1[g] + bn1) - xr1[g];
                k1r0[g] = kv0; k1r1[g] = kv1;
                pm = fmaxf(pm, fmaxf(fabsf(kv0), fabsf(kv1)));
            }

            // stage 2
            #pragma unroll
            for (int g = 0; g < 4; ++g) {
                xt0[g] = fmaf(a21, k1r0[g], xr0[g]);
                xt1[g] = fmaf(a21, k1r1[g], xr1[g]);
            }
            writeFrag(0, xt0, xt1);
            __syncthreads();
            acc0 = {0.f, 0.f, 0.f, 0.f}; acc1 = {0.f, 0.f, 0.f, 0.f};
            matmul(0, acc0, acc1);
            #pragma unroll
            for (int g = 0; g < 4; ++g) {
                k2r0[g] = tanh_fast(acc0[g] + bn0) - xt0[g];
                k2r1[g] = tanh_fast(acc1[g] + bn1) - xt1[g];
            }

            // stage 3
            #pragma unroll
            for (int g = 0; g < 4; ++g) {
                float t0 = fmaf(a31, k1r0[g], xr0[g]); t0 = fmaf(a32, k2r0[g], t0);
                float t1 = fmaf(a31, k1r1[g], xr1[g]); t1 = fmaf(a32, k2r1[g], t1);
                xt0[g] = t0; xt1[g] = t1;
            }
            writeFrag(1, xt0, xt1);
            __syncthreads();
            acc0 = {0.f, 0.f, 0.f, 0.f}; acc1 = {0.f, 0.f, 0.f, 0.f};
            matmul(1, acc0, acc1);
            #pragma unroll
            for (int g = 0; g < 4; ++g) {
                k3r0[g] = tanh_fast(acc0[g] + bn0) - xt0[g];
                k3r1[g] = tanh_fast(acc1[g] + bn1) - xt1[g];
            }

            // stage 4
            #pragma unroll
            for (int g = 0; g < 4; ++g) {
                float t0 = fmaf(a41, k1r0[g], xr0[g]); t0 = fmaf(a42, k2r0[g], t0); t0 = fmaf(a43, k3r0[g], t0);
                float t1 = fmaf(a41, k1r1[g], xr1[g]); t1 = fmaf(a42, k2r1[g], t1); t1 = fmaf(a43, k3r1[g], t1);
                xt0[g] = t0; xt1[g] = t1;
            }
            writeFrag(0, xt0, xt1);
            __syncthreads();
            acc0 = {0.f, 0.f, 0.f, 0.f}; acc1 = {0.f, 0.f, 0.f, 0.f};
            matmul(0, acc0, acc1);
            #pragma unroll
            for (int g = 0; g < 4; ++g) {
                k4r0[g] = tanh_fast(acc0[g] + bn0) - xt0[g];
                k4r1[g] = tanh_fast(acc1[g] + bn1) - xt1[g];
            }

            // stage 5
            #pragma unroll
            for (int g = 0; g < 4; ++g) {
                float t0 = fmaf(a51, k1r0[g], xr0[g]); t0 = fmaf(a52, k2r0[g], t0);
                t0 = fmaf(a53, k3r0[g], t0); t0 = fmaf(a54, k4r0[g], t0);
                float t1 = fmaf(a51, k1r1[g], xr1[g]); t1 = fmaf(a52, k2r1[g], t1);
                t1 = fmaf(a53, k3r1[g], t1); t1 = fmaf(a54, k4r1[g], t1);
                xt0[g] = t0; xt1[g] = t1;
            }
            writeFrag(1, xt0, xt1);
            __syncthreads();
            acc0 = {0.f, 0.f, 0.f, 0.f}; acc1 = {0.f, 0.f, 0.f, 0.f};
            matmul(1, acc0, acc1);
            #pragma unroll
            for (int g = 0; g < 4; ++g) {
                k5r0[g] = tanh_fast(acc0[g] + bn0) - xt0[g];
                k5r1[g] = tanh_fast(acc1[g] + bn1) - xt1[g];
            }

            // stage 6
            #pragma unroll
            for (int g = 0; g < 4; ++g) {
                float t0 = fmaf(a61, k1r0[g], xr0[g]); t0 = fmaf(a62, k2r0[g], t0);
                t0 = fmaf(a63, k3r0[g], t0); t0 = fmaf(a64, k4r0[g], t0); t0 = fmaf(a65, k5r0[g], t0);
                float t1 = fmaf(a61, k1r1[g], xr1[g]); t1 = fmaf(a62, k2r1[g], t1);
                t1 = fmaf(a63, k3r1[g], t1); t1 = fmaf(a64, k4r1[g], t1); t1 = fmaf(a65, k5r1[g], t1);
                xt0[g] = t0; xt1[g] = t1;
            }
            writeFrag(0, xt0, xt1);
            __syncthreads();
            acc0 = {0.f, 0.f, 0.f, 0.f}; acc1 = {0.f, 0.f, 0.f, 0.f};
            matmul(0, acc0, acc1);
            #pragma unroll
            for (int g = 0; g < 4; ++g) {
                float k60 = tanh_fast(acc0[g] + bn0) - xt0[g];
                float k61 = tanh_fast(acc1[g] + bn1) - xt1[g];
                float x4e0 = xr0[g] + c41 * k1r0[g] + c43 * k3r0[g] + c44 * k4r0[g] + c45 * k5r0[g];
                float x5e0 = xr0[g] + c51 * k1r0[g] + c53 * k3r0[g] + c54 * k4r0[g] + c55 * k5r0[g] + c56 * k60;
                float x4e1 = xr1[g] + c41 * k1r1[g] + c43 * k3r1[g] + c44 * k4r1[g] + c45 * k5r1[g];
                float x5e1 = xr1[g] + c51 * k1r1[g] + c53 * k3r1[g] + c54 * k4r1[g] + c55 * k5r1[g] + c56 * k61;
                xn[rowbase + (size_t)g * UNITS + n0] = x5e0;
                xn[rowbase + (size_t)g * UNITS + n1] = x5e1;
                em = fmaxf(em, fmaxf(fabsf(x5e0 - x4e0), fabsf(x5e1 - x4e1)));
            }
            // no end-of-chunk barrier needed: next chunk's first write goes to
            // buffer 1, current readers are on buffer 0; alternation re-aligns
            // because the stage count (6) is even.
        }

        blockAtomicMax2(&scal[it % 3], em, redbuf, tid);
        blockAtomicMax2(&scal[3 + it % 3], pm, redbuf, tid);

        grid.sync();

        if (tid == 0) {
            bc2[0] = __uint_as_float(atomicMax(&scal[it % 3], 0u));       // global err
            bc2[1] = __uint_as_float(atomicMax(&scal[3 + it % 3], 0u));   // global pvf max
        }
        __syncthreads();
        const float err = bc2[0];
        const float pvfmax = bc2[1];

        // reference checks cond BEFORE the body we just (speculatively) ran
        if (!((t <= 1000.0f) && (pvfmax >= 0.01f))) break;

        const bool accept = (err < 1.0e-3f) || (dt <= 0.01f);
        float dtn = 0.9f * dt * powf(1.0e-3f / (err + 1e-12f), 0.2f);
        dtn = fminf(fmaxf(dtn, 0.01f), 1.0f);

        if (accept) {
            t = t + dt;
            float* tmp = xc; xc = xn; xn = tmp;
        }
        dt = dtn;
    }

    // final x must end in d_out (content is final; any schedule OK)
    if (xc != xA) {
        const f32x4* src = (const f32x4*)xc;
        f32x4* dst = (f32x4*)xA;
        const int total = BATCH * UNITS / 4;
        for (int i = blockIdx.x * TPB + tid; i < total; i += gridDim.x * TPB)
            dst[i] = src[i];
    }
}

// ---- host ----------------------------------------------------------------
extern "C" void kernel_launch(void* const* d_in, const int* in_sizes, int n_in,
                              void* d_out, int out_size, void* d_ws, size_t ws_size,
                              hipStream_t stream)
{
    const float* x0 = (const float*)d_in[0];
    const float* W  = (const float*)d_in[1];
    const float* b  = (const float*)d_in[2];
    float* xA = (float*)d_out;

    const size_t xbytes = (size_t)BATCH * UNITS * sizeof(float);          // 32 MiB
    const size_t wfrag  = (size_t)UNITS * UNITS * sizeof(unsigned short); // 128 KiB

    char* ws = (char*)d_ws;
    unsigned* scal = (unsigned*)ws;                      // 32 B used
    unsigned short* WfH = (unsigned short*)(ws + 4096);
    unsigned short* WfL = (unsigned short*)(ws + 4096 + wfrag);
    float* xB = (float*)(ws + 4096 + 2 * wfrag);

    const size_t req = 4096 + 2 * wfrag + xbytes;        // ~32.3 MB
    if (ws_size < req) return;

    init_ws_kernel<<<(UNITS * UNITS) / 256, 256, 0, stream>>>(W, WfH, WfL, scal);
    (void)hipMemcpyAsync(xA, x0, xbytes, hipMemcpyDeviceToDevice, stream);

    int nb = 0;
    if (hipOccupancyMaxActiveBlocksPerMultiprocessor(&nb, hopfield_solver, TPB, 0) != hipSuccess || nb < 1)
        nb = 1;
    int ncu = 0;
    if (hipDeviceGetAttribute(&ncu, hipDeviceAttributeMultiprocessorCount, 0) != hipSuccess || ncu < 1)
        ncu = 256;
    int gridsz = nb * ncu;
    if (gridsz > NCHUNK) gridsz = NCHUNK;
    if (gridsz < 1) gridsz = 1;

    void* args[6];
    args[0] = (void*)&xA; args[1] = (void*)&xB; args[2] = (void*)&b;
    args[3] = (void*)&WfH; args[4] = (void*)&WfL; args[5] = (void*)&scal;
    (void)hipLaunchCooperativeKernel(hopfield_solver, dim3(gridsz), dim3(TPB), args, 0u, stream);
}

// Round 6
// 7793.736 us; speedup vs baseline: 7.8844x; 1.0366x over previous
//
#include <hip/hip_runtime.h>
#include <hip/hip_cooperative_groups.h>
#include <math.h>

namespace cg = cooperative_groups;

#define UNITS  256
#define BATCH  32768
#define R      16                 /* rows per chunk */
#define NCHUNK (BATCH / R)        /* 2048 */
#define TPB    1024               /* 16 waves: one 16-col n-tile per wave */

typedef float f32x4 __attribute__((ext_vector_type(4)));
typedef short s16x8 __attribute__((ext_vector_type(8)));

__device__ __forceinline__ unsigned bf16rn_bits(float v) {
    unsigned u = __float_as_uint(v);
    return (u + 0x7FFFu + ((u >> 16) & 1u)) >> 16;   // round-to-nearest-even
}

__device__ __forceinline__ float tanhd(float v) {
    // tanh(x) = 1 - 2/(exp(2x)+1); exact at +/-inf, no branches
    float e = __expf(v + v);
    return 1.0f - 2.0f / (e + 1.0f);
}

// padded frag layout: unit (16B) -> u16 offset; 16B pad after every 8 units
__device__ __forceinline__ int puidx(int unit) {
    return (unit << 3) + ((unit >> 3) << 3);
}

__device__ __forceinline__ void blockAtomicMax2(unsigned* addr, float v, float* redbuf, int tid)
{
    #pragma unroll
    for (int o = 32; o > 0; o >>= 1) v = fmaxf(v, __shfl_xor(v, o, 64));
    if ((tid & 63) == 0) redbuf[tid >> 6] = v;
    __syncthreads();
    if (tid == 0) {
        float m = redbuf[0];
        #pragma unroll
        for (int i = 1; i < TPB / 64; ++i) m = fmaxf(m, redbuf[i]);
        atomicMax(addr, __float_as_uint(m));   // values >= 0: uint order == float order
    }
    __syncthreads();
}

// ---- init: symmetric zero-diag Ws, split to bf16 hi/lo B-fragment order ----
__global__ void init_ws_kernel(const float* __restrict__ W,
                               unsigned short* __restrict__ WfH,
                               unsigned short* __restrict__ WfL,
                               unsigned* __restrict__ scal)
{
    const int i = blockIdx.x * 256 + threadIdx.x;    // 0..65535
    const int k = i >> 8, n = i & 255;
    float v = 0.5f * (W[(k << 8) + n] + W[(n << 8) + k]);
    if (k == n) v = 0.0f;
    unsigned hb = bf16rn_bits(v);
    float hf = __uint_as_float(hb << 16);
    unsigned lb = bf16rn_bits(v - hf);
    // fragment order: [nt(16)][ks(8)][lane(64)][slot(8)]
    const int nt = n >> 4, ks = k >> 5;
    const int lane = (n & 15) + (((k >> 3) & 3) << 4);
    const int slot = k & 7;
    const int off = ((nt * 8 + ks) * 64 + lane) * 8 + slot;
    WfH[off] = (unsigned short)hb;
    WfL[off] = (unsigned short)lb;
    if (i < 8) scal[i] = 0u;
}

// ---- persistent cooperative solver --------------------------------------
__global__ void __launch_bounds__(TPB, 4) hopfield_solver(
    float* __restrict__ xA, float* __restrict__ xB,
    const float* __restrict__ bvec,
    const s16x8* __restrict__ WfH, const s16x8* __restrict__ WfL,
    unsigned* __restrict__ scal)
{
    cg::grid_group grid = cg::this_grid();
    __shared__ __align__(16) unsigned short XH[2][4608];   // xt hi, double-buffered
    __shared__ __align__(16) unsigned short XL[4608];      // xt lo, stage-1 only
    __shared__ float redbuf[TPB / 64];
    __shared__ float bc2[2];

    const int tid = threadIdx.x;
    const int l = tid & 63, w = tid >> 6;        // 16 waves

    // C-layout ownership: wave w owns n-tile w; thread: col n0, rows mb..mb+3
    const int n0 = (w << 4) + (l & 15);
    const int mb = (l >> 4) << 2;
    const float bn0 = bvec[n0];

    // A-frag write target for element (m=mb+g, k-col=n0): unit=(n0>>5)*64+((n0>>3)&3)*16+m
    const int pb0 = puidx((n0 >> 5) * 64 + ((n0 >> 3) & 3) * 16 + mb) + (l & 7);
    // A-frag read base: unit = ks*64 + l -> byte-u16 offset ks*576 + lbase
    const int lbase = (l << 3) + ((l >> 3) << 3);

    // preload Ws B-fragments for this wave's n-tile (64 VGPR, persistent)
    s16x8 BH[8], BL[8];
    #pragma unroll
    for (int ks = 0; ks < 8; ++ks) {
        BH[ks] = WfH[(w * 8 + ks) * 64 + l];
        BL[ks] = WfL[(w * 8 + ks) * 64 + l];
    }

    // store 4 f32 as bf16-hi to buffer p (stages 2-6)
    auto writeH = [&](int p, const float (&v)[4]) {
        #pragma unroll
        for (int g = 0; g < 4; ++g)
            XH[p][pb0 + 8 * g] = (unsigned short)bf16rn_bits(v[g]);
    };
    // store hi+lo split (stage 1: full precision for pvf/k1)
    auto writeHL = [&](int p, const float (&v)[4]) {
        #pragma unroll
        for (int g = 0; g < 4; ++g) {
            unsigned hb = bf16rn_bits(v[g]);
            unsigned lb = bf16rn_bits(v[g] - __uint_as_float(hb << 16));
            XH[p][pb0 + 8 * g] = (unsigned short)hb;
            XL[pb0 + 8 * g]    = (unsigned short)lb;
        }
    };

    auto matmul2 = [&](int p, f32x4& acc) {   // xh*(Wh+Wl)
        #pragma unroll
        for (int ks = 0; ks < 8; ++ks) {
            const s16x8 aH = *(const s16x8*)&XH[p][ks * 576 + lbase];
            acc = __builtin_amdgcn_mfma_f32_16x16x32_bf16(aH, BH[ks], acc, 0, 0, 0);
            acc = __builtin_amdgcn_mfma_f32_16x16x32_bf16(aH, BL[ks], acc, 0, 0, 0);
        }
    };
    auto matmul3 = [&](int p, f32x4& acc) {   // + xl*Wh (stage 1)
        #pragma unroll
        for (int ks = 0; ks < 8; ++ks) {
            const s16x8 aH = *(const s16x8*)&XH[p][ks * 576 + lbase];
            const s16x8 aL = *(const s16x8*)&XL[ks * 576 + lbase];
            acc = __builtin_amdgcn_mfma_f32_16x16x32_bf16(aH, BH[ks], acc, 0, 0, 0);
            acc = __builtin_amdgcn_mfma_f32_16x16x32_bf16(aH, BL[ks], acc, 0, 0, 0);
            acc = __builtin_amdgcn_mfma_f32_16x16x32_bf16(aL, BH[ks], acc, 0, 0, 0);
        }
    };

    float* xc = xA;   // current x (d_out holds x0)
    float* xn = xB;
    float t = 0.0f, dt = 0.1f;

    for (int it = 0; it < 100000; ++it) {
        if (blockIdx.x == 0 && tid == 0) {
            scal[(it + 1) % 3] = 0u;          // err slot for next iter
            scal[3 + (it + 1) % 3] = 0u;      // pvf slot for next iter
        }

        // dt-premultiplied RKF coefficients (wave-uniform scalars -> SGPR)
        const float a21 = 0.25f * dt;
        const float a31 = (float)(3.0 / 32.0) * dt,   a32 = (float)(9.0 / 32.0) * dt;
        const float a41 = (float)(1932.0 / 2197.0) * dt, a42 = (float)(-7200.0 / 2197.0) * dt,
                    a43 = (float)(7296.0 / 2197.0) * dt;
        const float a51 = (float)(439.0 / 216.0) * dt, a52 = -8.0f * dt,
                    a53 = (float)(3680.0 / 513.0) * dt, a54 = (float)(-845.0 / 4104.0) * dt;
        const float a61 = (float)(-8.0 / 27.0) * dt,  a62 = 2.0f * dt,
                    a63 = (float)(-3544.0 / 2565.0) * dt, a64 = (float)(1859.0 / 4104.0) * dt,
                    a65 = (float)(-11.0 / 40.0) * dt;
        const float c41 = (float)(25.0 / 216.0) * dt, c43 = (float)(1408.0 / 2565.0) * dt,
                    c44 = (float)(2197.0 / 4104.0) * dt, c45 = -0.2f * dt;
        const float c51 = (float)(16.0 / 135.0) * dt, c53 = (float)(6656.0 / 12825.0) * dt,
                    c54 = (float)(28561.0 / 56430.0) * dt, c55 = (float)(-9.0 / 50.0) * dt,
                    c56 = (float)(2.0 / 55.0) * dt;

        float em = 0.0f, pm = 0.0f;

        for (int ch = blockIdx.x; ch < NCHUNK; ch += gridDim.x) {
            const size_t rowbase = (size_t)(ch * R + mb) * UNITS;

            float xr[4], k1r[4], k2r[4], k3r[4], k4r[4], k5r[4], xt[4];
            f32x4 acc;

            #pragma unroll
            for (int g = 0; g < 4; ++g)
                xr[g] = xc[rowbase + (size_t)g * UNITS + n0];

            // stage 1: k1 = pvf(x), full hi/lo precision (stop condition + k1)
            writeHL(1, xr);
            __syncthreads();
            acc = {0.f, 0.f, 0.f, 0.f};
            matmul3(1, acc);
            #pragma unroll
            for (int g = 0; g < 4; ++g) {
                float kv = tanhd(acc[g] + bn0) - xr[g];
                k1r[g] = kv;
                pm = fmaxf(pm, fabsf(kv));
            }

            // stage 2
            #pragma unroll
            for (int g = 0; g < 4; ++g) xt[g] = fmaf(a21, k1r[g], xr[g]);
            writeH(0, xt);
            __syncthreads();
            acc = {0.f, 0.f, 0.f, 0.f};
            matmul2(0, acc);
            #pragma unroll
            for (int g = 0; g < 4; ++g) k2r[g] = tanhd(acc[g] + bn0) - xt[g];

            // stage 3
            #pragma unroll
            for (int g = 0; g < 4; ++g) {
                float v = fmaf(a31, k1r[g], xr[g]); v = fmaf(a32, k2r[g], v);
                xt[g] = v;
            }
            writeH(1, xt);
            __syncthreads();
            acc = {0.f, 0.f, 0.f, 0.f};
            matmul2(1, acc);
            #pragma unroll
            for (int g = 0; g < 4; ++g) k3r[g] = tanhd(acc[g] + bn0) - xt[g];

            // stage 4
            #pragma unroll
            for (int g = 0; g < 4; ++g) {
                float v = fmaf(a41, k1r[g], xr[g]); v = fmaf(a42, k2r[g], v);
                v = fmaf(a43, k3r[g], v);
                xt[g] = v;
            }
            writeH(0, xt);
            __syncthreads();
            acc = {0.f, 0.f, 0.f, 0.f};
            matmul2(0, acc);
            #pragma unroll
            for (int g = 0; g < 4; ++g) k4r[g] = tanhd(acc[g] + bn0) - xt[g];

            // stage 5
            #pragma unroll
            for (int g = 0; g < 4; ++g) {
                float v = fmaf(a51, k1r[g], xr[g]); v = fmaf(a52, k2r[g], v);
                v = fmaf(a53, k3r[g], v); v = fmaf(a54, k4r[g], v);
                xt[g] = v;
            }
            writeH(1, xt);
            __syncthreads();
            acc = {0.f, 0.f, 0.f, 0.f};
            matmul2(1, acc);
            #pragma unroll
            for (int g = 0; g < 4; ++g) k5r[g] = tanhd(acc[g] + bn0) - xt[g];

            // stage 6 + fused err/x5 epilogue
            #pragma unroll
            for (int g = 0; g < 4; ++g) {
                float v = fmaf(a61, k1r[g], xr[g]); v = fmaf(a62, k2r[g], v);
                v = fmaf(a63, k3r[g], v); v = fmaf(a64, k4r[g], v); v = fmaf(a65, k5r[g], v);
                xt[g] = v;
            }
            writeH(0, xt);
            __syncthreads();
            acc = {0.f, 0.f, 0.f, 0.f};
            matmul2(0, acc);
            #pragma unroll
            for (int g = 0; g < 4; ++g) {
                float k6 = tanhd(acc[g] + bn0) - xt[g];
                float x4e = xr[g] + c41 * k1r[g] + c43 * k3r[g] + c44 * k4r[g] + c45 * k5r[g];
                float x5e = xr[g] + c51 * k1r[g] + c53 * k3r[g] + c54 * k4r[g] + c55 * k5r[g] + c56 * k6;
                xn[rowbase + (size_t)g * UNITS + n0] = x5e;
                em = fmaxf(em, fabsf(x5e - x4e));
            }
            // no end-of-chunk barrier: next chunk's first write (XH[1]/XL) is
            // protected by the stage-6 barrier all waves just passed.
        }

        blockAtomicMax2(&scal[it % 3], em, redbuf, tid);
        blockAtomicMax2(&scal[3 + it % 3], pm, redbuf, tid);

        grid.sync();

        if (tid == 0) {
            bc2[0] = __uint_as_float(atomicMax(&scal[it % 3], 0u));       // global err
            bc2[1] = __uint_as_float(atomicMax(&scal[3 + it % 3], 0u));   // global pvf max
        }
        __syncthreads();
        const float err = bc2[0];
        const float pvfmax = bc2[1];

        // reference checks cond BEFORE the body we just (speculatively) ran
        if (!((t <= 1000.0f) && (pvfmax >= 0.01f))) break;

        const bool accept = (err < 1.0e-3f) || (dt <= 0.01f);
        float dtn = 0.9f * dt * powf(1.0e-3f / (err + 1e-12f), 0.2f);
        dtn = fminf(fmaxf(dtn, 0.01f), 1.0f);

        if (accept) {
            t = t + dt;
            float* tmp = xc; xc = xn; xn = tmp;
        }
        dt = dtn;
    }

    // final x must end in d_out (content is final; any schedule OK)
    if (xc != xA) {
        const f32x4* src = (const f32x4*)xc;
        f32x4* dst = (f32x4*)xA;
        const int total = BATCH * UNITS / 4;
        for (int i = blockIdx.x * TPB + tid; i < total; i += gridDim.x * TPB)
            dst[i] = src[i];
    }
}

// ---- host ----------------------------------------------------------------
extern "C" void kernel_launch(void* const* d_in, const int* in_sizes, int n_in,
                              void* d_out, int out_size, void* d_ws, size_t ws_size,
                              hipStream_t stream)
{
    const float* x0 = (const float*)d_in[0];
    const float* W  = (const float*)d_in[1];
    const float* b  = (const float*)d_in[2];
    float* xA = (float*)d_out;

    const size_t xbytes = (size_t)BATCH * UNITS * sizeof(float);          // 32 MiB
    const size_t wfrag  = (size_t)UNITS * UNITS * sizeof(unsigned short); // 128 KiB

    char* ws = (char*)d_ws;
    unsigned* scal = (unsigned*)ws;                      // 32 B used
    unsigned short* WfH = (unsigned short*)(ws + 4096);
    unsigned short* WfL = (unsigned short*)(ws + 4096 + wfrag);
    float* xB = (float*)(ws + 4096 + 2 * wfrag);

    const size_t req = 4096 + 2 * wfrag + xbytes;        // ~32.3 MB
    if (ws_size < req) return;

    init_ws_kernel<<<(UNITS * UNITS) / 256, 256, 0, stream>>>(W, WfH, WfL, scal);
    (void)hipMemcpyAsync(xA, x0, xbytes, hipMemcpyDeviceToDevice, stream);

    int nb = 0;
    if (hipOccupancyMaxActiveBlocksPerMultiprocessor(&nb, hopfield_solver, TPB, 0) != hipSuccess || nb < 1)
        nb = 1;
    int ncu = 0;
    if (hipDeviceGetAttribute(&ncu, hipDeviceAttributeMultiprocessorCount, 0) != hipSuccess || ncu < 1)
        ncu = 256;
    int gridsz = nb * ncu;
    if (gridsz > NCHUNK) gridsz = NCHUNK;
    if (gridsz < 1) gridsz = 1;

    void* args[6];
    args[0] = (void*)&xA; args[1] = (void*)&xB; args[2] = (void*)&b;
    args[3] = (void*)&WfH; args[4] = (void*)&WfL; args[5] = (void*)&scal;
    (void)hipLaunchCooperativeKernel(hopfield_solver, dim3(gridsz), dim3(TPB), args, 0u, stream);
}